// Round 1
// baseline (6880.125 us; speedup 1.0000x reference)
//
#include <hip/hip_runtime.h>
#include <cstdint>

// ---------------------------------------------------------------------------
// GCN: 3x GCNConv(+ELU) + linear head.
// deg/dinv/norm are layer-invariant -> computed once into workspace.
// Per layer: xw = act(h) @ W ; agg = dinv^2*xw + b ; scatter-add norm*xw[src].
// ---------------------------------------------------------------------------

__global__ void __launch_bounds__(256) deg_kernel(const int* __restrict__ dst,
                                                  const float* __restrict__ w,
                                                  float* __restrict__ deg, int E) {
    int e = blockIdx.x * 256 + threadIdx.x;
    if (e < E) unsafeAtomicAdd(&deg[dst[e]], w[e]);
}

__global__ void __launch_bounds__(256) dinv_kernel(float* __restrict__ deg, int N) {
    int i = blockIdx.x * 256 + threadIdx.x;
    if (i < N) deg[i] = rsqrtf(deg[i] + 1.0f);  // +1 self loop; always > 0
}

__global__ void __launch_bounds__(256) norm_kernel(const int* __restrict__ src,
                                                   const int* __restrict__ dst,
                                                   const float* __restrict__ w,
                                                   const float* __restrict__ dinv,
                                                   float* __restrict__ nrm, int E) {
    int e = blockIdx.x * 256 + threadIdx.x;
    if (e < E) nrm[e] = dinv[src[e]] * w[e] * dinv[dst[e]];
}

// x[N,256] @ W[256,16] -> xw[N,16]. 16 rows x 16 cols per 256-thread block.
__global__ void __launch_bounds__(256) gemm_x16(const float* __restrict__ x,
                                                const float* __restrict__ W,
                                                float* __restrict__ xw, int N) {
    __shared__ float Ws[256 * 16];
    for (int i = threadIdx.x; i < 256 * 16; i += 256) Ws[i] = W[i];
    __syncthreads();
    int c = threadIdx.x & 15;
    int rl = threadIdx.x >> 4;
    int r = blockIdx.x * 16 + rl;
    if (r >= N) return;
    const float4* x4 = (const float4*)(x + (size_t)r * 256);
    float acc = 0.f;
#pragma unroll 8
    for (int k4 = 0; k4 < 64; ++k4) {
        float4 v = x4[k4];
        const float* wr = &Ws[k4 * 64 + c];
        acc += v.x * wr[0] + v.y * wr[16] + v.z * wr[32] + v.w * wr[48];
    }
    xw[(size_t)r * 16 + c] = acc;
}

// in[N,K] (ELU applied on load) @ W[K,F] (+bias) -> out[N,F]
template <int K, int F, bool BIAS>
__global__ void __launch_bounds__(256) gemm_small(const float* __restrict__ in,
                                                  const float* __restrict__ W,
                                                  const float* __restrict__ bias,
                                                  float* __restrict__ out, int N) {
    constexpr int ROWS = 256 / F;
    __shared__ float Ws[K * F];
    __shared__ float Is[ROWS * K];
    for (int i = threadIdx.x; i < K * F; i += 256) Ws[i] = W[i];
    int r0 = blockIdx.x * ROWS;
    for (int i = threadIdx.x; i < ROWS * K; i += 256) {
        float v = in[(size_t)r0 * K + i];
        Is[i] = v > 0.f ? v : expm1f(v);  // ELU
    }
    __syncthreads();
    int c = threadIdx.x % F;
    int rl = threadIdx.x / F;
    float acc = BIAS ? bias[c] : 0.f;
#pragma unroll
    for (int k = 0; k < K; ++k) acc += Is[rl * K + k] * Ws[k * F + c];
    out[(size_t)(r0 + rl) * F + c] = acc;
}

// agg[i] = dinv[node]^2 * xw[i] + bias[c]   (self-loop + bias init)
template <int F>
__global__ void __launch_bounds__(256) init_agg(const float* __restrict__ xw,
                                                const float* __restrict__ dinv,
                                                const float* __restrict__ bias,
                                                float* __restrict__ agg, int N) {
    int i = blockIdx.x * 256 + threadIdx.x;
    if (i >= N * F) return;
    int node = i / F;
    int c = i % F;
    float di = dinv[node];
    agg[i] = di * di * xw[i] + bias[c];
}

// scatter-add: agg[dst] += norm[e] * xw[src].  One thread = one float4 chunk.
template <int F>
__global__ void __launch_bounds__(256) edge_agg(const int* __restrict__ src,
                                                const int* __restrict__ dst,
                                                const float* __restrict__ nrm,
                                                const float* __restrict__ xw,
                                                float* __restrict__ agg, int E) {
    constexpr int Q = F / 4;
    long long t = (long long)blockIdx.x * 256 + threadIdx.x;
    long long e = t / Q;
    if (e >= E) return;
    int q = (int)(t % Q);
    int s = src[e], d = dst[e];
    float nm = nrm[e];
    float4 v = ((const float4*)xw)[(size_t)s * Q + q];
    float* ap = &agg[((size_t)d * Q + q) * 4];
    unsafeAtomicAdd(ap + 0, nm * v.x);
    unsafeAtomicAdd(ap + 1, nm * v.y);
    unsafeAtomicAdd(ap + 2, nm * v.z);
    unsafeAtomicAdd(ap + 3, nm * v.w);
}

extern "C" void kernel_launch(void* const* d_in, const int* in_sizes, int n_in,
                              void* d_out, int out_size, void* d_ws, size_t ws_size,
                              hipStream_t stream) {
    const float* x  = (const float*)d_in[0];
    const int*   ei = (const int*)d_in[1];
    const float* w  = (const float*)d_in[2];
    const float* W0 = (const float*)d_in[3];
    const float* b0 = (const float*)d_in[4];
    const float* W1 = (const float*)d_in[5];
    const float* b1 = (const float*)d_in[6];
    const float* W2 = (const float*)d_in[7];
    const float* b2 = (const float*)d_in[8];
    const float* Wm = (const float*)d_in[9];
    const float* bm = (const float*)d_in[10];
    float* out = (float*)d_out;

    const int N = in_sizes[0] / 256;
    const int E = in_sizes[2];
    const int* src = ei;
    const int* dst = ei + E;

    char* ws = (char*)d_ws;
    size_t off = 0;
    auto alloc = [&](size_t bytes) {
        void* p = ws + off;
        off = (off + bytes + 255) & ~(size_t)255;
        return p;
    };
    float* dinv = (float*)alloc((size_t)N * 4);        // deg -> dinv (in place)
    float* nrm  = (float*)alloc((size_t)E * 4);
    float* XW   = (float*)alloc((size_t)N * 32 * 4);
    float* AGG  = (float*)alloc((size_t)N * 32 * 4);

    hipMemsetAsync(dinv, 0, (size_t)N * 4, stream);

    int ebl = (E + 255) / 256;
    deg_kernel<<<ebl, 256, 0, stream>>>(dst, w, dinv, E);
    dinv_kernel<<<(N + 255) / 256, 256, 0, stream>>>(dinv, N);
    norm_kernel<<<ebl, 256, 0, stream>>>(src, dst, w, dinv, nrm, E);

    // ---- layer 0: 256 -> 16
    gemm_x16<<<(N + 15) / 16, 256, 0, stream>>>(x, W0, XW, N);
    init_agg<16><<<(int)(((size_t)N * 16 + 255) / 256), 256, 0, stream>>>(XW, dinv, b0, AGG, N);
    edge_agg<16><<<(int)(((long long)E * 4 + 255) / 256), 256, 0, stream>>>(src, dst, nrm, XW, AGG, E);

    // ---- layer 1: 16 -> 32 (ELU on input)
    gemm_small<16, 32, false><<<(N + 7) / 8, 256, 0, stream>>>(AGG, W1, nullptr, XW, N);
    init_agg<32><<<(int)(((size_t)N * 32 + 255) / 256), 256, 0, stream>>>(XW, dinv, b1, AGG, N);
    edge_agg<32><<<(int)(((long long)E * 8 + 255) / 256), 256, 0, stream>>>(src, dst, nrm, XW, AGG, E);

    // ---- layer 2: 32 -> 32 (ELU on input)
    gemm_small<32, 32, false><<<(N + 7) / 8, 256, 0, stream>>>(AGG, W2, nullptr, XW, N);
    init_agg<32><<<(int)(((size_t)N * 32 + 255) / 256), 256, 0, stream>>>(XW, dinv, b2, AGG, N);
    edge_agg<32><<<(int)(((long long)E * 8 + 255) / 256), 256, 0, stream>>>(src, dst, nrm, XW, AGG, E);

    // ---- head: elu(h2) @ Wm + bm -> out
    gemm_small<32, 16, true><<<(N + 15) / 16, 256, 0, stream>>>(AGG, Wm, bm, out, N);
}

// Round 2
// 1673.770 us; speedup vs baseline: 4.1106x; 4.1106x over previous
//
#include <hip/hip_runtime.h>
#include <cstdint>

// ---------------------------------------------------------------------------
// GCN: 3x GCNConv(+ELU) + linear head.
// Strategy: build dst-sorted CSR once (counting sort), then each layer's
// aggregation is a gather-reduce (no fp32 atomics). deg/dinv/norm are
// layer-invariant; norm is stored packed with src in the permuted edge array.
// ---------------------------------------------------------------------------

// Pass 1: per-dst edge counts (int) + weighted degree (float).
__global__ void __launch_bounds__(256) hist_kernel(const int* __restrict__ dst,
                                                   const float* __restrict__ w,
                                                   int* __restrict__ cnt,
                                                   float* __restrict__ deg, int E) {
    int e = blockIdx.x * 256 + threadIdx.x;
    if (e < E) {
        int d = dst[e];
        atomicAdd(&cnt[d], 1);
        unsafeAtomicAdd(&deg[d], w[e]);
    }
}

__global__ void __launch_bounds__(256) dinv_kernel(float* __restrict__ deg, int N) {
    int i = blockIdx.x * 256 + threadIdx.x;
    if (i < N) deg[i] = rsqrtf(deg[i] + 1.0f);  // +1 self loop; always > 0
}

// Single-block exclusive scan of cnt[N] -> row_ptr[N+1], duplicate into cursor.
__global__ void __launch_bounds__(1024) scan_kernel(const int* __restrict__ cnt,
                                                    int* __restrict__ row_ptr,
                                                    int* __restrict__ cursor, int N) {
    __shared__ int part[1024];
    int t = threadIdx.x;
    int per = (N + 1023) / 1024;
    int beg = t * per;
    int end = beg + per;
    if (beg > N) beg = N;
    if (end > N) end = N;
    int s = 0;
    for (int i = beg; i < end; ++i) s += cnt[i];
    part[t] = s;
    __syncthreads();
    for (int off = 1; off < 1024; off <<= 1) {
        int v = part[t];
        int add = (t >= off) ? part[t - off] : 0;
        __syncthreads();
        part[t] = v + add;
        __syncthreads();
    }
    int run = (t > 0) ? part[t - 1] : 0;  // exclusive base for this thread
    for (int i = beg; i < end; ++i) {
        row_ptr[i] = run;
        cursor[i] = run;
        run += cnt[i];
    }
    if (beg < N && end == N) row_ptr[N] = run;  // == E
}

// Pass 2: scatter edges into CSR order; pack (src, norm) into int2.
__global__ void __launch_bounds__(256) scatter_kernel(const int* __restrict__ src,
                                                      const int* __restrict__ dst,
                                                      const float* __restrict__ w,
                                                      const float* __restrict__ dinv,
                                                      int* __restrict__ cursor,
                                                      int2* __restrict__ perm, int E) {
    int e = blockIdx.x * 256 + threadIdx.x;
    if (e >= E) return;
    int s = src[e], d = dst[e];
    float nm = dinv[s] * w[e] * dinv[d];
    int pos = atomicAdd(&cursor[d], 1);
    int2 p;
    p.x = s;
    p.y = __float_as_int(nm);
    perm[pos] = p;
}

// x[N,256] @ W[256,16] -> xw[N,16]. 16 rows x 16 cols per 256-thread block.
__global__ void __launch_bounds__(256) gemm_x16(const float* __restrict__ x,
                                                const float* __restrict__ W,
                                                float* __restrict__ xw, int N) {
    __shared__ float Ws[256 * 16];
    for (int i = threadIdx.x; i < 256 * 16; i += 256) Ws[i] = W[i];
    __syncthreads();
    int c = threadIdx.x & 15;
    int rl = threadIdx.x >> 4;
    int r = blockIdx.x * 16 + rl;
    if (r >= N) return;
    const float4* x4 = (const float4*)(x + (size_t)r * 256);
    float acc = 0.f;
#pragma unroll 8
    for (int k4 = 0; k4 < 64; ++k4) {
        float4 v = x4[k4];
        const float* wr = &Ws[k4 * 64 + c];
        acc += v.x * wr[0] + v.y * wr[16] + v.z * wr[32] + v.w * wr[48];
    }
    xw[(size_t)r * 16 + c] = acc;
}

// in[N,K] (ELU applied on load) @ W[K,F] (+bias) -> out[N,F]
template <int K, int F, bool BIAS>
__global__ void __launch_bounds__(256) gemm_small(const float* __restrict__ in,
                                                  const float* __restrict__ W,
                                                  const float* __restrict__ bias,
                                                  float* __restrict__ out, int N) {
    constexpr int ROWS = 256 / F;
    __shared__ float Ws[K * F];
    __shared__ float Is[ROWS * K];
    for (int i = threadIdx.x; i < K * F; i += 256) Ws[i] = W[i];
    int r0 = blockIdx.x * ROWS;
    for (int i = threadIdx.x; i < ROWS * K; i += 256) {
        float v = in[(size_t)r0 * K + i];
        Is[i] = v > 0.f ? v : expm1f(v);  // ELU
    }
    __syncthreads();
    int c = threadIdx.x % F;
    int rl = threadIdx.x / F;
    float acc = BIAS ? bias[c] : 0.f;
#pragma unroll
    for (int k = 0; k < K; ++k) acc += Is[rl * K + k] * Ws[k * F + c];
    out[(size_t)(r0 + rl) * F + c] = acc;
}

// CSR gather-aggregate: out[n,c] = b[c] + dinv[n]^2*xw[n,c] + sum_j nrm_j*xw[src_j,c]
template <int F>
__global__ void __launch_bounds__(256) agg_csr(const int* __restrict__ row_ptr,
                                               const int2* __restrict__ perm,
                                               const float* __restrict__ xw,
                                               const float* __restrict__ dinv,
                                               const float* __restrict__ bias,
                                               float* __restrict__ out, int N) {
    constexpr int G = 256 / F;
    int node = blockIdx.x * G + threadIdx.x / F;
    int c = threadIdx.x % F;
    if (node >= N) return;
    float di = dinv[node];
    float acc = di * di * xw[(size_t)node * F + c] + bias[c];
    int beg = row_ptr[node];
    int end = row_ptr[node + 1];
    int j = beg;
    // 2-deep unroll with independent accumulators for a little ILP
    float acc2 = 0.f;
    for (; j + 1 < end; j += 2) {
        int2 p0 = perm[j];
        int2 p1 = perm[j + 1];
        acc  += __int_as_float(p0.y) * xw[(size_t)p0.x * F + c];
        acc2 += __int_as_float(p1.y) * xw[(size_t)p1.x * F + c];
    }
    if (j < end) {
        int2 p0 = perm[j];
        acc += __int_as_float(p0.y) * xw[(size_t)p0.x * F + c];
    }
    out[(size_t)node * F + c] = acc + acc2;
}

extern "C" void kernel_launch(void* const* d_in, const int* in_sizes, int n_in,
                              void* d_out, int out_size, void* d_ws, size_t ws_size,
                              hipStream_t stream) {
    const float* x  = (const float*)d_in[0];
    const int*   ei = (const int*)d_in[1];
    const float* w  = (const float*)d_in[2];
    const float* W0 = (const float*)d_in[3];
    const float* b0 = (const float*)d_in[4];
    const float* W1 = (const float*)d_in[5];
    const float* b1 = (const float*)d_in[6];
    const float* W2 = (const float*)d_in[7];
    const float* b2 = (const float*)d_in[8];
    const float* Wm = (const float*)d_in[9];
    const float* bm = (const float*)d_in[10];
    float* out = (float*)d_out;

    const int N = in_sizes[0] / 256;
    const int E = in_sizes[2];
    const int* src = ei;
    const int* dst = ei + E;

    char* ws = (char*)d_ws;
    size_t off = 0;
    auto alloc = [&](size_t bytes) {
        void* p = ws + off;
        off = (off + bytes + 255) & ~(size_t)255;
        return p;
    };
    float* dinv    = (float*)alloc((size_t)N * 4);        // deg -> dinv in place
    int*   cnt     = (int*)alloc((size_t)N * 4);
    int*   row_ptr = (int*)alloc(((size_t)N + 1) * 4);
    int*   cursor  = (int*)alloc((size_t)N * 4);
    int2*  perm    = (int2*)alloc((size_t)E * 8);
    float* XW      = (float*)alloc((size_t)N * 32 * 4);
    float* AGG     = (float*)alloc((size_t)N * 32 * 4);

    hipMemsetAsync(dinv, 0, (size_t)N * 4, stream);
    hipMemsetAsync(cnt, 0, (size_t)N * 4, stream);

    int ebl = (E + 255) / 256;
    int nbl = (N + 255) / 256;

    // ---- build CSR (layer-invariant)
    hist_kernel<<<ebl, 256, 0, stream>>>(dst, w, cnt, dinv, E);
    dinv_kernel<<<nbl, 256, 0, stream>>>(dinv, N);
    scan_kernel<<<1, 1024, 0, stream>>>(cnt, row_ptr, cursor, N);
    scatter_kernel<<<ebl, 256, 0, stream>>>(src, dst, w, dinv, cursor, perm, E);

    // ---- layer 0: 256 -> 16
    gemm_x16<<<(N + 15) / 16, 256, 0, stream>>>(x, W0, XW, N);
    agg_csr<16><<<(N + 15) / 16, 256, 0, stream>>>(row_ptr, perm, XW, dinv, b0, AGG, N);

    // ---- layer 1: 16 -> 32 (ELU on input)
    gemm_small<16, 32, false><<<(N + 7) / 8, 256, 0, stream>>>(AGG, W1, nullptr, XW, N);
    agg_csr<32><<<(N + 7) / 8, 256, 0, stream>>>(row_ptr, perm, XW, dinv, b1, AGG, N);

    // ---- layer 2: 32 -> 32 (ELU on input)
    gemm_small<32, 32, false><<<(N + 7) / 8, 256, 0, stream>>>(AGG, W2, nullptr, XW, N);
    agg_csr<32><<<(N + 7) / 8, 256, 0, stream>>>(row_ptr, perm, XW, dinv, b2, AGG, N);

    // ---- head: elu(h2) @ Wm + bm -> out
    gemm_small<32, 16, true><<<(N + 15) / 16, 256, 0, stream>>>(AGG, Wm, bm, out, N);
}

// Round 3
// 897.082 us; speedup vs baseline: 7.6695x; 1.8658x over previous
//
#include <hip/hip_runtime.h>
#include <cstdint>

// ---------------------------------------------------------------------------
// GCN: 3x GCNConv(+ELU) + linear head.
// CSR built with a two-level LDS counting sort (no per-edge global atomics):
//   A) bucket histogram (bucket = dst>>8, 256 nodes/bucket)
//   B) scatter edges into bucket regions (LDS cursors, per-block reservation)
//   C) per-bucket LDS sort -> perm[(src,w)], row_ptr, dinv
//   D) norm computed in place over CSR
// Layers: gemm (+ELU fused) then gather-aggregate over CSR.
// ---------------------------------------------------------------------------

// ---- Pass A: per-bucket edge counts. bucket = dst >> 8.
__global__ void __launch_bounds__(256) bucket_hist(const int* __restrict__ dst,
                                                   int* __restrict__ bcnt,
                                                   int E, int nbuck, int chunk) {
    __shared__ int h[512];
    for (int i = threadIdx.x; i < 512; i += 256) h[i] = 0;
    __syncthreads();
    int c0 = blockIdx.x * chunk;
    int c1 = min(E, c0 + chunk);
    for (int i = c0 + threadIdx.x; i < c1; i += 256)
        atomicAdd(&h[((unsigned)dst[i]) >> 8], 1);
    __syncthreads();
    for (int i = threadIdx.x; i < nbuck; i += 256)
        if (h[i]) atomicAdd(&bcnt[i], h[i]);
}

// ---- scan of bucket counts -> boff[nbuck+1], global cursors.
__global__ void __launch_bounds__(512) bucket_scan(const int* __restrict__ bcnt,
                                                   int* __restrict__ boff,
                                                   int* __restrict__ gcur,
                                                   int nbuck) {
    __shared__ int part[512];
    int t = threadIdx.x;
    part[t] = (t < nbuck) ? bcnt[t] : 0;
    __syncthreads();
    for (int off = 1; off < 512; off <<= 1) {
        int v = part[t];
        int a = (t >= off) ? part[t - off] : 0;
        __syncthreads();
        part[t] = v + a;
        __syncthreads();
    }
    if (t < nbuck) {
        int excl = (t > 0) ? part[t - 1] : 0;
        boff[t] = excl;
        gcur[t] = excl;
        if (t == nbuck - 1) boff[nbuck] = part[t];  // == E
    }
}

// ---- Pass B: scatter edges into bucket regions. pack (local_dst<<24|src, w).
__global__ void __launch_bounds__(256) bucket_scatter(const int* __restrict__ src,
                                                      const int* __restrict__ dst,
                                                      const float* __restrict__ w,
                                                      int* __restrict__ gcur,
                                                      int2* __restrict__ bedge,
                                                      int E, int nbuck, int chunk) {
    __shared__ int lcnt[512];
    __shared__ int lbase[512];
    int c0 = blockIdx.x * chunk;
    int c1 = min(E, c0 + chunk);
    for (int i = threadIdx.x; i < nbuck; i += 256) lcnt[i] = 0;
    __syncthreads();
    for (int i = c0 + threadIdx.x; i < c1; i += 256)
        atomicAdd(&lcnt[((unsigned)dst[i]) >> 8], 1);
    __syncthreads();
    for (int i = threadIdx.x; i < nbuck; i += 256) {
        int c = lcnt[i];
        lbase[i] = c ? atomicAdd(&gcur[i], c) : 0;
        lcnt[i] = 0;
    }
    __syncthreads();
    for (int i = c0 + threadIdx.x; i < c1; i += 256) {
        unsigned d = (unsigned)dst[i];
        int b = d >> 8;
        int pos = lbase[b] + atomicAdd(&lcnt[b], 1);
        int2 p;
        p.x = (int)(((d & 255u) << 24) | (unsigned)src[i]);
        p.y = __float_as_int(w[i]);
        bedge[pos] = p;
    }
}

// ---- Pass C: one block per bucket. LDS 256-bin sort + deg -> perm/row_ptr/dinv.
__global__ void __launch_bounds__(256) bucket_sort(const int* __restrict__ boff,
                                                   const int2* __restrict__ bedge,
                                                   int2* __restrict__ perm,
                                                   int* __restrict__ row_ptr,
                                                   float* __restrict__ dinv,
                                                   int N, int E) {
    __shared__ int cnt[256];
    __shared__ float deg[256];
    __shared__ int part[256];
    __shared__ int cur[256];
    int b = blockIdx.x;
    int base = boff[b];
    int m = boff[b + 1] - base;
    int t = threadIdx.x;
    cnt[t] = 0;
    deg[t] = 0.f;
    __syncthreads();
    for (int i = t; i < m; i += 256) {
        int2 e = bedge[base + i];
        unsigned l = ((unsigned)e.x) >> 24;
        atomicAdd(&cnt[l], 1);
        atomicAdd(&deg[l], __int_as_float(e.y));
    }
    __syncthreads();
    part[t] = cnt[t];
    __syncthreads();
    for (int off = 1; off < 256; off <<= 1) {
        int v = part[t];
        int a = (t >= off) ? part[t - off] : 0;
        __syncthreads();
        part[t] = v + a;
        __syncthreads();
    }
    int excl = (t > 0) ? part[t - 1] : 0;
    cur[t] = excl;
    int node = b * 256 + t;
    if (node < N) {
        row_ptr[node] = base + excl;
        dinv[node] = rsqrtf(deg[t] + 1.0f);
    }
    if (b == 0 && t == 0) row_ptr[N] = E;
    __syncthreads();
    for (int i = t; i < m; i += 256) {
        int2 e = bedge[base + i];
        unsigned ux = (unsigned)e.x;
        unsigned l = ux >> 24;
        int pos = base + atomicAdd(&cur[l], 1);
        int2 p;
        p.x = (int)(ux & 0xFFFFFFu);
        p.y = e.y;
        perm[pos] = p;
    }
}

// ---- Pass D: w -> norm in place. One wave per node.
__global__ void __launch_bounds__(256) norm_csr(const int* __restrict__ row_ptr,
                                                const float* __restrict__ dinv,
                                                int2* __restrict__ perm, int N) {
    int node = blockIdx.x * 4 + (threadIdx.x >> 6);
    if (node >= N) return;
    int lane = threadIdx.x & 63;
    float scale = dinv[node];
    int beg = row_ptr[node], end = row_ptr[node + 1];
    for (int j = beg + lane; j < end; j += 64) {
        int2 p = perm[j];
        float nm = dinv[p.x] * __int_as_float(p.y) * scale;
        perm[j].y = __float_as_int(nm);
    }
}

// x[N,256] @ W[256,16] -> xw[N,16]. 16 rows x 16 cols per 256-thread block.
__global__ void __launch_bounds__(256) gemm_x16(const float* __restrict__ x,
                                                const float* __restrict__ W,
                                                float* __restrict__ xw, int N) {
    __shared__ float Ws[256 * 16];
    for (int i = threadIdx.x; i < 256 * 16; i += 256) Ws[i] = W[i];
    __syncthreads();
    int c = threadIdx.x & 15;
    int rl = threadIdx.x >> 4;
    int r = blockIdx.x * 16 + rl;
    if (r >= N) return;
    const float4* x4 = (const float4*)(x + (size_t)r * 256);
    float acc = 0.f;
#pragma unroll 8
    for (int k4 = 0; k4 < 64; ++k4) {
        float4 v = x4[k4];
        const float* wr = &Ws[k4 * 64 + c];
        acc += v.x * wr[0] + v.y * wr[16] + v.z * wr[32] + v.w * wr[48];
    }
    xw[(size_t)r * 16 + c] = acc;
}

// in[N,K] (ELU applied on load) @ W[K,F] (+bias) -> out[N,F]
template <int K, int F, bool BIAS>
__global__ void __launch_bounds__(256) gemm_small(const float* __restrict__ in,
                                                  const float* __restrict__ W,
                                                  const float* __restrict__ bias,
                                                  float* __restrict__ out, int N) {
    constexpr int ROWS = 256 / F;
    __shared__ float Ws[K * F];
    __shared__ float Is[ROWS * K];
    for (int i = threadIdx.x; i < K * F; i += 256) Ws[i] = W[i];
    int r0 = blockIdx.x * ROWS;
    for (int i = threadIdx.x; i < ROWS * K; i += 256) {
        float v = in[(size_t)r0 * K + i];
        Is[i] = v > 0.f ? v : expm1f(v);  // ELU
    }
    __syncthreads();
    int c = threadIdx.x % F;
    int rl = threadIdx.x / F;
    float acc = BIAS ? bias[c] : 0.f;
#pragma unroll
    for (int k = 0; k < K; ++k) acc += Is[rl * K + k] * Ws[k * F + c];
    out[(size_t)(r0 + rl) * F + c] = acc;
}

// CSR gather-aggregate: out[n,c] = b[c] + dinv[n]^2*xw[n,c] + sum_j nrm_j*xw[src_j,c]
template <int F>
__global__ void __launch_bounds__(256) agg_csr(const int* __restrict__ row_ptr,
                                               const int2* __restrict__ perm,
                                               const float* __restrict__ xw,
                                               const float* __restrict__ dinv,
                                               const float* __restrict__ bias,
                                               float* __restrict__ out, int N) {
    constexpr int G = 256 / F;
    int node = blockIdx.x * G + threadIdx.x / F;
    int c = threadIdx.x % F;
    if (node >= N) return;
    float di = dinv[node];
    float acc = di * di * xw[(size_t)node * F + c] + bias[c];
    int beg = row_ptr[node];
    int end = row_ptr[node + 1];
    int j = beg;
    float acc2 = 0.f;
    for (; j + 1 < end; j += 2) {
        int2 p0 = perm[j];
        int2 p1 = perm[j + 1];
        acc  += __int_as_float(p0.y) * xw[(size_t)p0.x * F + c];
        acc2 += __int_as_float(p1.y) * xw[(size_t)p1.x * F + c];
    }
    if (j < end) {
        int2 p0 = perm[j];
        acc += __int_as_float(p0.y) * xw[(size_t)p0.x * F + c];
    }
    out[(size_t)node * F + c] = acc + acc2;
}

extern "C" void kernel_launch(void* const* d_in, const int* in_sizes, int n_in,
                              void* d_out, int out_size, void* d_ws, size_t ws_size,
                              hipStream_t stream) {
    const float* x  = (const float*)d_in[0];
    const int*   ei = (const int*)d_in[1];
    const float* w  = (const float*)d_in[2];
    const float* W0 = (const float*)d_in[3];
    const float* b0 = (const float*)d_in[4];
    const float* W1 = (const float*)d_in[5];
    const float* b1 = (const float*)d_in[6];
    const float* W2 = (const float*)d_in[7];
    const float* b2 = (const float*)d_in[8];
    const float* Wm = (const float*)d_in[9];
    const float* bm = (const float*)d_in[10];
    float* out = (float*)d_out;

    const int N = in_sizes[0] / 256;
    const int E = in_sizes[2];
    const int* src = ei;
    const int* dst = ei + E;
    const int nbuck = (N + 255) >> 8;  // 256 nodes per bucket; requires N <= 131072

    char* ws = (char*)d_ws;
    size_t off = 0;
    auto alloc = [&](size_t bytes) {
        void* p = ws + off;
        off = (off + bytes + 255) & ~(size_t)255;
        return p;
    };
    float* dinv    = (float*)alloc((size_t)N * 4);
    int*   row_ptr = (int*)alloc(((size_t)N + 1) * 4);
    int*   bcnt    = (int*)alloc(520 * 4);
    int*   boff    = (int*)alloc(520 * 4);
    int*   gcur    = (int*)alloc(520 * 4);
    int2*  bedge   = (int2*)alloc((size_t)E * 8);
    int2*  perm    = (int2*)alloc((size_t)E * 8);
    float* XW      = (float*)alloc((size_t)N * 32 * 4);
    float* AGG     = (float*)alloc((size_t)N * 32 * 4);

    hipMemsetAsync(bcnt, 0, 520 * 4, stream);

    const int CH = 8192;
    const int sblk = (E + CH - 1) / CH;

    // ---- build CSR (layer-invariant)
    bucket_hist<<<sblk, 256, 0, stream>>>(dst, bcnt, E, nbuck, CH);
    bucket_scan<<<1, 512, 0, stream>>>(bcnt, boff, gcur, nbuck);
    bucket_scatter<<<sblk, 256, 0, stream>>>(src, dst, w, gcur, bedge, E, nbuck, CH);
    bucket_sort<<<nbuck, 256, 0, stream>>>(boff, bedge, perm, row_ptr, dinv, N, E);
    norm_csr<<<(N + 3) / 4, 256, 0, stream>>>(row_ptr, dinv, perm, N);

    // ---- layer 0: 256 -> 16
    gemm_x16<<<(N + 15) / 16, 256, 0, stream>>>(x, W0, XW, N);
    agg_csr<16><<<(N + 15) / 16, 256, 0, stream>>>(row_ptr, perm, XW, dinv, b0, AGG, N);

    // ---- layer 1: 16 -> 32 (ELU on input)
    gemm_small<16, 32, false><<<(N + 7) / 8, 256, 0, stream>>>(AGG, W1, nullptr, XW, N);
    agg_csr<32><<<(N + 7) / 8, 256, 0, stream>>>(row_ptr, perm, XW, dinv, b1, AGG, N);

    // ---- layer 2: 32 -> 32 (ELU on input)
    gemm_small<32, 32, false><<<(N + 7) / 8, 256, 0, stream>>>(AGG, W2, nullptr, XW, N);
    agg_csr<32><<<(N + 7) / 8, 256, 0, stream>>>(row_ptr, perm, XW, dinv, b2, AGG, N);

    // ---- head: elu(h2) @ Wm + bm -> out
    gemm_small<32, 16, true><<<(N + 15) / 16, 256, 0, stream>>>(AGG, Wm, bm, out, N);
}

// Round 4
// 710.878 us; speedup vs baseline: 9.6784x; 1.2619x over previous
//
#include <hip/hip_runtime.h>
#include <cstdint>

// ---------------------------------------------------------------------------
// GCN: 3x GCNConv(+ELU) + linear head.
// CSR built with a two-level LDS counting sort (no per-edge global atomics).
// Aggregation uses A(XW) = (AX)W associativity so the 3 gather passes run at
// F=16,16,32, each as float4-gathers with 4-deep unroll (latency hiding).
// Pipeline:
//   XW = x@W0            (gemm_x16)
//   h1 = elu(A.XW + b0)  (agg4<16> w/ bias+ELU)
//   AG1 = A.h1           (agg4<16>)
//   h2 = elu(AG1@W1+b1)  (gemm_small<16,32> ELU out)
//   AG2 = A.h2           (agg4<32>)
//   h3 = elu(AG2@W2+b2)  (gemm_small<32,32> ELU out)
//   out = h3@Wm + bm     (gemm_small<32,16>)
// ---------------------------------------------------------------------------

// ---- Pass A: per-bucket edge counts. bucket = dst >> 8.
__global__ void __launch_bounds__(256) bucket_hist(const int* __restrict__ dst,
                                                   int* __restrict__ bcnt,
                                                   int E, int nbuck, int chunk) {
    __shared__ int h[512];
    for (int i = threadIdx.x; i < 512; i += 256) h[i] = 0;
    __syncthreads();
    int c0 = blockIdx.x * chunk;
    int c1 = min(E, c0 + chunk);
    for (int i = c0 + threadIdx.x; i < c1; i += 256)
        atomicAdd(&h[((unsigned)dst[i]) >> 8], 1);
    __syncthreads();
    for (int i = threadIdx.x; i < nbuck; i += 256)
        if (h[i]) atomicAdd(&bcnt[i], h[i]);
}

// ---- scan of bucket counts -> boff[nbuck+1], global cursors.
__global__ void __launch_bounds__(512) bucket_scan(const int* __restrict__ bcnt,
                                                   int* __restrict__ boff,
                                                   int* __restrict__ gcur,
                                                   int nbuck) {
    __shared__ int part[512];
    int t = threadIdx.x;
    part[t] = (t < nbuck) ? bcnt[t] : 0;
    __syncthreads();
    for (int off = 1; off < 512; off <<= 1) {
        int v = part[t];
        int a = (t >= off) ? part[t - off] : 0;
        __syncthreads();
        part[t] = v + a;
        __syncthreads();
    }
    if (t < nbuck) {
        int excl = (t > 0) ? part[t - 1] : 0;
        boff[t] = excl;
        gcur[t] = excl;
        if (t == nbuck - 1) boff[nbuck] = part[t];  // == E
    }
}

// ---- Pass B: scatter edges into bucket regions. pack (local_dst<<24|src, w).
__global__ void __launch_bounds__(256) bucket_scatter(const int* __restrict__ src,
                                                      const int* __restrict__ dst,
                                                      const float* __restrict__ w,
                                                      int* __restrict__ gcur,
                                                      int2* __restrict__ bedge,
                                                      int E, int nbuck, int chunk) {
    __shared__ int lcnt[512];
    __shared__ int lbase[512];
    int c0 = blockIdx.x * chunk;
    int c1 = min(E, c0 + chunk);
    for (int i = threadIdx.x; i < nbuck; i += 256) lcnt[i] = 0;
    __syncthreads();
    for (int i = c0 + threadIdx.x; i < c1; i += 256)
        atomicAdd(&lcnt[((unsigned)dst[i]) >> 8], 1);
    __syncthreads();
    for (int i = threadIdx.x; i < nbuck; i += 256) {
        int c = lcnt[i];
        lbase[i] = c ? atomicAdd(&gcur[i], c) : 0;
        lcnt[i] = 0;
    }
    __syncthreads();
    for (int i = c0 + threadIdx.x; i < c1; i += 256) {
        unsigned d = (unsigned)dst[i];
        int b = d >> 8;
        int pos = lbase[b] + atomicAdd(&lcnt[b], 1);
        int2 p;
        p.x = (int)(((d & 255u) << 24) | (unsigned)src[i]);
        p.y = __float_as_int(w[i]);
        bedge[pos] = p;
    }
}

// ---- Pass C: one block per bucket. LDS 256-bin sort + deg -> perm/row_ptr/dinv.
__global__ void __launch_bounds__(256) bucket_sort(const int* __restrict__ boff,
                                                   const int2* __restrict__ bedge,
                                                   int2* __restrict__ perm,
                                                   int* __restrict__ row_ptr,
                                                   float* __restrict__ dinv,
                                                   int N, int E) {
    __shared__ int cnt[256];
    __shared__ float deg[256];
    __shared__ int part[256];
    __shared__ int cur[256];
    int b = blockIdx.x;
    int base = boff[b];
    int m = boff[b + 1] - base;
    int t = threadIdx.x;
    cnt[t] = 0;
    deg[t] = 0.f;
    __syncthreads();
    for (int i = t; i < m; i += 256) {
        int2 e = bedge[base + i];
        unsigned l = ((unsigned)e.x) >> 24;
        atomicAdd(&cnt[l], 1);
        atomicAdd(&deg[l], __int_as_float(e.y));
    }
    __syncthreads();
    part[t] = cnt[t];
    __syncthreads();
    for (int off = 1; off < 256; off <<= 1) {
        int v = part[t];
        int a = (t >= off) ? part[t - off] : 0;
        __syncthreads();
        part[t] = v + a;
        __syncthreads();
    }
    int excl = (t > 0) ? part[t - 1] : 0;
    cur[t] = excl;
    int node = b * 256 + t;
    if (node < N) {
        row_ptr[node] = base + excl;
        dinv[node] = rsqrtf(deg[t] + 1.0f);
    }
    if (b == 0 && t == 0) row_ptr[N] = E;
    __syncthreads();
    for (int i = t; i < m; i += 256) {
        int2 e = bedge[base + i];
        unsigned ux = (unsigned)e.x;
        unsigned l = ux >> 24;
        int pos = base + atomicAdd(&cur[l], 1);
        int2 p;
        p.x = (int)(ux & 0xFFFFFFu);
        p.y = e.y;
        perm[pos] = p;
    }
}

// ---- Pass D: w -> norm in place. One wave per node.
__global__ void __launch_bounds__(256) norm_csr(const int* __restrict__ row_ptr,
                                                const float* __restrict__ dinv,
                                                int2* __restrict__ perm, int N) {
    int node = blockIdx.x * 4 + (threadIdx.x >> 6);
    if (node >= N) return;
    int lane = threadIdx.x & 63;
    float scale = dinv[node];
    int beg = row_ptr[node], end = row_ptr[node + 1];
    for (int j = beg + lane; j < end; j += 64) {
        int2 p = perm[j];
        float nm = dinv[p.x] * __int_as_float(p.y) * scale;
        perm[j].y = __float_as_int(nm);
    }
}

// x[N,256] @ W[256,16] -> xw[N,16]. 16 rows x 16 cols per 256-thread block.
__global__ void __launch_bounds__(256) gemm_x16(const float* __restrict__ x,
                                                const float* __restrict__ W,
                                                float* __restrict__ xw, int N) {
    __shared__ float Ws[256 * 16];
    for (int i = threadIdx.x; i < 256 * 16; i += 256) Ws[i] = W[i];
    __syncthreads();
    int c = threadIdx.x & 15;
    int rl = threadIdx.x >> 4;
    int r = blockIdx.x * 16 + rl;
    if (r >= N) return;
    const float4* x4 = (const float4*)(x + (size_t)r * 256);
    float acc = 0.f;
#pragma unroll 8
    for (int k4 = 0; k4 < 64; ++k4) {
        float4 v = x4[k4];
        const float* wr = &Ws[k4 * 64 + c];
        acc += v.x * wr[0] + v.y * wr[16] + v.z * wr[32] + v.w * wr[48];
    }
    xw[(size_t)r * 16 + c] = acc;
}

// in[N,K] @ W[K,F] + bias -> out[N,F], optional ELU on output.
template <int K, int F, bool OUT_ELU>
__global__ void __launch_bounds__(256) gemm_small(const float* __restrict__ in,
                                                  const float* __restrict__ W,
                                                  const float* __restrict__ bias,
                                                  float* __restrict__ out, int N) {
    constexpr int ROWS = 256 / F;
    __shared__ float Ws[K * F];
    __shared__ float Is[ROWS * K];
    for (int i = threadIdx.x; i < K * F; i += 256) Ws[i] = W[i];
    int r0 = blockIdx.x * ROWS;
    for (int i = threadIdx.x; i < ROWS * K; i += 256)
        Is[i] = in[(size_t)r0 * K + i];
    __syncthreads();
    int c = threadIdx.x % F;
    int rl = threadIdx.x / F;
    float acc = bias[c];
#pragma unroll
    for (int k = 0; k < K; ++k) acc += Is[rl * K + k] * Ws[k * F + c];
    if (OUT_ELU) acc = acc > 0.f ? acc : expm1f(acc);
    out[(size_t)(r0 + rl) * F + c] = acc;
}

// CSR gather-aggregate with float4 gathers + 4-deep unroll.
// out[n,:] = [bias +] dinv[n]^2*xw[n,:] + sum_j nrm_j*xw[src_j,:]  [, ELU]
template <int F, bool BIAS_ELU>
__global__ void __launch_bounds__(256) agg4(const int* __restrict__ row_ptr,
                                            const int2* __restrict__ perm,
                                            const float* __restrict__ xw,
                                            const float* __restrict__ dinv,
                                            const float* __restrict__ bias,
                                            float* __restrict__ out, int N) {
    constexpr int G = F / 4;              // lanes per node
    constexpr int NPB = 256 / G;          // nodes per block
    int node = blockIdx.x * NPB + threadIdx.x / G;
    int q = threadIdx.x % G;
    if (node >= N) return;
    const float4* xw4 = (const float4*)xw;
    float di = dinv[node];
    float4 s = xw4[(size_t)node * G + q];
    float d2 = di * di;
    float4 a0 = {d2 * s.x, d2 * s.y, d2 * s.z, d2 * s.w};
    float4 a1 = {0.f, 0.f, 0.f, 0.f};
    float4 a2 = {0.f, 0.f, 0.f, 0.f};
    float4 a3 = {0.f, 0.f, 0.f, 0.f};
    int beg = row_ptr[node];
    int end = row_ptr[node + 1];
    int j = beg;
    for (; j + 3 < end; j += 4) {
        int2 p0 = perm[j];
        int2 p1 = perm[j + 1];
        int2 p2 = perm[j + 2];
        int2 p3 = perm[j + 3];
        float4 v0 = xw4[(size_t)p0.x * G + q];
        float4 v1 = xw4[(size_t)p1.x * G + q];
        float4 v2 = xw4[(size_t)p2.x * G + q];
        float4 v3 = xw4[(size_t)p3.x * G + q];
        float n0 = __int_as_float(p0.y);
        float n1 = __int_as_float(p1.y);
        float n2 = __int_as_float(p2.y);
        float n3 = __int_as_float(p3.y);
        a0.x += n0 * v0.x; a0.y += n0 * v0.y; a0.z += n0 * v0.z; a0.w += n0 * v0.w;
        a1.x += n1 * v1.x; a1.y += n1 * v1.y; a1.z += n1 * v1.z; a1.w += n1 * v1.w;
        a2.x += n2 * v2.x; a2.y += n2 * v2.y; a2.z += n2 * v2.z; a2.w += n2 * v2.w;
        a3.x += n3 * v3.x; a3.y += n3 * v3.y; a3.z += n3 * v3.z; a3.w += n3 * v3.w;
    }
    for (; j < end; ++j) {
        int2 p0 = perm[j];
        float4 v0 = xw4[(size_t)p0.x * G + q];
        float n0 = __int_as_float(p0.y);
        a0.x += n0 * v0.x; a0.y += n0 * v0.y; a0.z += n0 * v0.z; a0.w += n0 * v0.w;
    }
    float4 r;
    r.x = (a0.x + a1.x) + (a2.x + a3.x);
    r.y = (a0.y + a1.y) + (a2.y + a3.y);
    r.z = (a0.z + a1.z) + (a2.z + a3.z);
    r.w = (a0.w + a1.w) + (a2.w + a3.w);
    if (BIAS_ELU) {
        float4 b4 = ((const float4*)bias)[q];
        r.x += b4.x; r.y += b4.y; r.z += b4.z; r.w += b4.w;
        r.x = r.x > 0.f ? r.x : expm1f(r.x);
        r.y = r.y > 0.f ? r.y : expm1f(r.y);
        r.z = r.z > 0.f ? r.z : expm1f(r.z);
        r.w = r.w > 0.f ? r.w : expm1f(r.w);
    }
    ((float4*)out)[(size_t)node * G + q] = r;
}

extern "C" void kernel_launch(void* const* d_in, const int* in_sizes, int n_in,
                              void* d_out, int out_size, void* d_ws, size_t ws_size,
                              hipStream_t stream) {
    const float* x  = (const float*)d_in[0];
    const int*   ei = (const int*)d_in[1];
    const float* w  = (const float*)d_in[2];
    const float* W0 = (const float*)d_in[3];
    const float* b0 = (const float*)d_in[4];
    const float* W1 = (const float*)d_in[5];
    const float* b1 = (const float*)d_in[6];
    const float* W2 = (const float*)d_in[7];
    const float* b2 = (const float*)d_in[8];
    const float* Wm = (const float*)d_in[9];
    const float* bm = (const float*)d_in[10];
    float* out = (float*)d_out;

    const int N = in_sizes[0] / 256;
    const int E = in_sizes[2];
    const int* src = ei;
    const int* dst = ei + E;
    const int nbuck = (N + 255) >> 8;  // 256 nodes per bucket; requires N <= 131072

    char* ws = (char*)d_ws;
    size_t off = 0;
    auto alloc = [&](size_t bytes) {
        void* p = ws + off;
        off = (off + bytes + 255) & ~(size_t)255;
        return p;
    };
    float* dinv    = (float*)alloc((size_t)N * 4);
    int*   row_ptr = (int*)alloc(((size_t)N + 1) * 4);
    int*   bcnt    = (int*)alloc(520 * 4);
    int*   boff    = (int*)alloc(520 * 4);
    int*   gcur    = (int*)alloc(520 * 4);
    int2*  bedge   = (int2*)alloc((size_t)E * 8);
    int2*  perm    = (int2*)alloc((size_t)E * 8);
    float* BUF_A   = (float*)alloc((size_t)N * 32 * 4);
    float* BUF_B   = (float*)alloc((size_t)N * 32 * 4);

    hipMemsetAsync(bcnt, 0, 520 * 4, stream);

    const int CH = 8192;
    const int sblk = (E + CH - 1) / CH;

    // ---- build CSR (layer-invariant)
    bucket_hist<<<sblk, 256, 0, stream>>>(dst, bcnt, E, nbuck, CH);
    bucket_scan<<<1, 512, 0, stream>>>(bcnt, boff, gcur, nbuck);
    bucket_scatter<<<sblk, 256, 0, stream>>>(src, dst, w, gcur, bedge, E, nbuck, CH);
    bucket_sort<<<nbuck, 256, 0, stream>>>(boff, bedge, perm, row_ptr, dinv, N, E);
    norm_csr<<<(N + 3) / 4, 256, 0, stream>>>(row_ptr, dinv, perm, N);

    // ---- layer 0: XW = x@W0 ; h1 = elu(A.XW + b0)
    gemm_x16<<<(N + 15) / 16, 256, 0, stream>>>(x, W0, BUF_A, N);
    agg4<16, true><<<(N + 63) / 64, 256, 0, stream>>>(row_ptr, perm, BUF_A, dinv, b0, BUF_B, N);

    // ---- layer 1: AG1 = A.h1 ; h2 = elu(AG1@W1 + b1)
    agg4<16, false><<<(N + 63) / 64, 256, 0, stream>>>(row_ptr, perm, BUF_B, dinv, nullptr, BUF_A, N);
    gemm_small<16, 32, true><<<(N + 7) / 8, 256, 0, stream>>>(BUF_A, W1, b1, BUF_B, N);

    // ---- layer 2: AG2 = A.h2 ; h3 = elu(AG2@W2 + b2)
    agg4<32, false><<<(N + 31) / 32, 256, 0, stream>>>(row_ptr, perm, BUF_B, dinv, nullptr, BUF_A, N);
    gemm_small<32, 32, true><<<(N + 7) / 8, 256, 0, stream>>>(BUF_A, W2, b2, BUF_B, N);

    // ---- head: out = h3@Wm + bm
    gemm_small<32, 16, false><<<(N + 15) / 16, 256, 0, stream>>>(BUF_B, Wm, bm, out, N);
}

// Round 5
// 621.758 us; speedup vs baseline: 11.0656x; 1.1433x over previous
//
#include <hip/hip_runtime.h>
#include <cstdint>

// ---------------------------------------------------------------------------
// GCN: 3x GCNConv(+ELU) + linear head.
// CSR build (no per-edge global atomics, coalesced writes):
//   A) bucket_hist: global per-bucket counts (bucket = dst>>8)
//   B) bucket_scan: prefix -> boff/gcur
//   C) bucket_scatter: per-block LDS counting-sort reorder of a 4096-edge
//      tile, then run-contiguous coalesced writes into bedge
//   D) sort_deg: per-bucket LDS hist/deg -> row_ptr, dinv
//   E) sort_scatter: per-bucket scatter bedge->perm with norm fused
//      (nm = dinv[src]*w*dinv[dst])
// Layers use A(XW)=(AX)W so gather passes run at F=16,16,32 (agg4: float4
// gathers, 4-deep unroll).
// ---------------------------------------------------------------------------

// ---- Pass A: per-bucket edge counts. bucket = dst >> 8.
__global__ void __launch_bounds__(256) bucket_hist(const int* __restrict__ dst,
                                                   int* __restrict__ bcnt,
                                                   int E, int nbuck, int chunk) {
    __shared__ int h[512];
    for (int i = threadIdx.x; i < 512; i += 256) h[i] = 0;
    __syncthreads();
    int c0 = blockIdx.x * chunk;
    int c1 = min(E, c0 + chunk);
    for (int i = c0 + threadIdx.x; i < c1; i += 256)
        atomicAdd(&h[((unsigned)dst[i]) >> 8], 1);
    __syncthreads();
    for (int i = threadIdx.x; i < nbuck; i += 256)
        if (h[i]) atomicAdd(&bcnt[i], h[i]);
}

// ---- scan of bucket counts -> boff[nbuck+1], global cursors.
__global__ void __launch_bounds__(512) bucket_scan(const int* __restrict__ bcnt,
                                                   int* __restrict__ boff,
                                                   int* __restrict__ gcur,
                                                   int nbuck) {
    __shared__ int part[512];
    int t = threadIdx.x;
    part[t] = (t < nbuck) ? bcnt[t] : 0;
    __syncthreads();
    for (int off = 1; off < 512; off <<= 1) {
        int v = part[t];
        int a = (t >= off) ? part[t - off] : 0;
        __syncthreads();
        part[t] = v + a;
        __syncthreads();
    }
    if (t < nbuck) {
        int excl = (t > 0) ? part[t - 1] : 0;
        boff[t] = excl;
        gcur[t] = excl;
        if (t == nbuck - 1) boff[nbuck] = part[t];  // == E
    }
}

// ---- Pass C: LDS-reorder scatter. TILE=4096 edges/block.
// Stage tile in registers, per-block counting sort into LDS, write runs out
// from consecutive lanes (coalesced, full sectors).
__global__ void __launch_bounds__(256) bucket_scatter(const int* __restrict__ src,
                                                      const int* __restrict__ dst,
                                                      const float* __restrict__ w,
                                                      int* __restrict__ gcur,
                                                      int2* __restrict__ bedge,
                                                      int E) {
    constexpr int TILE = 4096;
    __shared__ int h[512];
    __shared__ int lcnt[512];
    __shared__ int lofs[512];
    __shared__ int gb[512];
    __shared__ int part[256];
    __shared__ int2 sedge[TILE];
    __shared__ unsigned short sbuck[TILE];

    int t = threadIdx.x;
    int c0 = blockIdx.x * TILE;
    int mtile = min(TILE, E - c0);

    for (int i = t; i < 512; i += 256) { h[i] = 0; lcnt[i] = 0; }
    __syncthreads();

    // stage 16 edges/thread in registers (int4 loads where in-bounds)
    int  my_dst[16];
    int  my_src[16];
    float my_w[16];
#pragma unroll
    for (int k = 0; k < 4; ++k) {
        int e0 = c0 + (t + k * 256) * 4;
        if (e0 + 4 <= E) {
            int4 d4 = *(const int4*)(dst + e0);
            int4 s4 = *(const int4*)(src + e0);
            float4 w4 = *(const float4*)(w + e0);
            my_dst[k*4+0]=d4.x; my_dst[k*4+1]=d4.y; my_dst[k*4+2]=d4.z; my_dst[k*4+3]=d4.w;
            my_src[k*4+0]=s4.x; my_src[k*4+1]=s4.y; my_src[k*4+2]=s4.z; my_src[k*4+3]=s4.w;
            my_w[k*4+0]=w4.x;  my_w[k*4+1]=w4.y;  my_w[k*4+2]=w4.z;  my_w[k*4+3]=w4.w;
        } else {
#pragma unroll
            for (int j = 0; j < 4; ++j) {
                int e = e0 + j;
                bool ok = e < E;
                my_dst[k*4+j] = ok ? dst[e] : -1;
                my_src[k*4+j] = ok ? src[e] : 0;
                my_w[k*4+j]   = ok ? w[e] : 0.f;
            }
        }
    }
    // tile histogram
#pragma unroll
    for (int j = 0; j < 16; ++j)
        if (my_dst[j] >= 0) atomicAdd(&h[((unsigned)my_dst[j]) >> 8], 1);
    __syncthreads();

    // scan (2 bins/thread) + global reservation
    int a0 = h[2 * t], a1 = h[2 * t + 1];
    int s = a0 + a1;
    part[t] = s;
    __syncthreads();
    for (int off = 1; off < 256; off <<= 1) {
        int v = part[t];
        int a = (t >= off) ? part[t - off] : 0;
        __syncthreads();
        part[t] = v + a;
        __syncthreads();
    }
    int excl = part[t] - s;
    lofs[2 * t] = excl;
    lofs[2 * t + 1] = excl + a0;
    if (a0) gb[2 * t] = atomicAdd(&gcur[2 * t], a0) - excl;
    if (a1) gb[2 * t + 1] = atomicAdd(&gcur[2 * t + 1], a1) - (excl + a0);
    __syncthreads();

    // LDS counting-sort scatter
#pragma unroll
    for (int j = 0; j < 16; ++j) {
        int d = my_dst[j];
        if (d < 0) continue;
        unsigned ud = (unsigned)d;
        int b = ud >> 8;
        int p = lofs[b] + atomicAdd(&lcnt[b], 1);
        int2 e;
        e.x = (int)(((ud & 255u) << 24) | (unsigned)my_src[j]);
        e.y = __float_as_int(my_w[j]);
        sedge[p] = e;
        sbuck[p] = (unsigned short)b;
    }
    __syncthreads();

    // run-contiguous write-out: consecutive lanes -> consecutive addresses
    for (int i = t; i < mtile; i += 256) {
        int b = sbuck[i];
        bedge[gb[b] + i] = sedge[i];
    }
}

// ---- Pass D: per-bucket deg -> row_ptr, dinv.
__global__ void __launch_bounds__(256) sort_deg(const int* __restrict__ boff,
                                                const int2* __restrict__ bedge,
                                                int* __restrict__ row_ptr,
                                                float* __restrict__ dinv,
                                                int N, int E) {
    __shared__ int cnt[256];
    __shared__ float deg[256];
    __shared__ int part[256];
    int b = blockIdx.x;
    int base = boff[b];
    int m = boff[b + 1] - base;
    int t = threadIdx.x;
    cnt[t] = 0;
    deg[t] = 0.f;
    __syncthreads();
    for (int i = t; i < m; i += 256) {
        int2 e = bedge[base + i];
        unsigned l = ((unsigned)e.x) >> 24;
        atomicAdd(&cnt[l], 1);
        atomicAdd(&deg[l], __int_as_float(e.y));
    }
    __syncthreads();
    part[t] = cnt[t];
    __syncthreads();
    for (int off = 1; off < 256; off <<= 1) {
        int v = part[t];
        int a = (t >= off) ? part[t - off] : 0;
        __syncthreads();
        part[t] = v + a;
        __syncthreads();
    }
    int excl = part[t] - cnt[t];
    int node = b * 256 + t;
    if (node < N) {
        row_ptr[node] = base + excl;
        dinv[node] = rsqrtf(deg[t] + 1.0f);
    }
    if (b == 0 && t == 0) row_ptr[N] = E;
}

// ---- Pass E: bedge -> perm (CSR order) with fused norm.
__global__ void __launch_bounds__(256) sort_scatter(const int* __restrict__ boff,
                                                    const int2* __restrict__ bedge,
                                                    const int* __restrict__ row_ptr,
                                                    const float* __restrict__ dinv,
                                                    int2* __restrict__ perm, int N) {
    __shared__ int cur[256];
    __shared__ float sdinv[256];
    int b = blockIdx.x;
    int base = boff[b];
    int m = boff[b + 1] - base;
    int t = threadIdx.x;
    int node = b * 256 + t;
    cur[t] = (node < N) ? row_ptr[node] : 0;
    sdinv[t] = (node < N) ? dinv[node] : 0.f;
    __syncthreads();
    for (int i = t; i < m; i += 256) {
        int2 e = bedge[base + i];
        unsigned ux = (unsigned)e.x;
        unsigned l = ux >> 24;
        int sidx = (int)(ux & 0xFFFFFFu);
        float nm = dinv[sidx] * __int_as_float(e.y) * sdinv[l];
        int pos = atomicAdd(&cur[l], 1);
        int2 p;
        p.x = sidx;
        p.y = __float_as_int(nm);
        perm[pos] = p;
    }
}

// x[N,256] @ W[256,16] -> xw[N,16]. 16 rows x 16 cols per 256-thread block.
__global__ void __launch_bounds__(256) gemm_x16(const float* __restrict__ x,
                                                const float* __restrict__ W,
                                                float* __restrict__ xw, int N) {
    __shared__ float Ws[256 * 16];
    for (int i = threadIdx.x; i < 256 * 16; i += 256) Ws[i] = W[i];
    __syncthreads();
    int c = threadIdx.x & 15;
    int rl = threadIdx.x >> 4;
    int r = blockIdx.x * 16 + rl;
    if (r >= N) return;
    const float4* x4 = (const float4*)(x + (size_t)r * 256);
    float acc = 0.f;
#pragma unroll 8
    for (int k4 = 0; k4 < 64; ++k4) {
        float4 v = x4[k4];
        const float* wr = &Ws[k4 * 64 + c];
        acc += v.x * wr[0] + v.y * wr[16] + v.z * wr[32] + v.w * wr[48];
    }
    xw[(size_t)r * 16 + c] = acc;
}

// in[N,K] @ W[K,F] + bias -> out[N,F], optional ELU on output.
template <int K, int F, bool OUT_ELU>
__global__ void __launch_bounds__(256) gemm_small(const float* __restrict__ in,
                                                  const float* __restrict__ W,
                                                  const float* __restrict__ bias,
                                                  float* __restrict__ out, int N) {
    constexpr int ROWS = 256 / F;
    __shared__ float Ws[K * F];
    __shared__ float Is[ROWS * K];
    for (int i = threadIdx.x; i < K * F; i += 256) Ws[i] = W[i];
    int r0 = blockIdx.x * ROWS;
    for (int i = threadIdx.x; i < ROWS * K; i += 256)
        Is[i] = in[(size_t)r0 * K + i];
    __syncthreads();
    int c = threadIdx.x % F;
    int rl = threadIdx.x / F;
    float acc = bias[c];
#pragma unroll
    for (int k = 0; k < K; ++k) acc += Is[rl * K + k] * Ws[k * F + c];
    if (OUT_ELU) acc = acc > 0.f ? acc : expm1f(acc);
    out[(size_t)(r0 + rl) * F + c] = acc;
}

// CSR gather-aggregate with float4 gathers + 4-deep unroll.
template <int F, bool BIAS_ELU>
__global__ void __launch_bounds__(256) agg4(const int* __restrict__ row_ptr,
                                            const int2* __restrict__ perm,
                                            const float* __restrict__ xw,
                                            const float* __restrict__ dinv,
                                            const float* __restrict__ bias,
                                            float* __restrict__ out, int N) {
    constexpr int G = F / 4;              // lanes per node
    constexpr int NPB = 256 / G;          // nodes per block
    int node = blockIdx.x * NPB + threadIdx.x / G;
    int q = threadIdx.x % G;
    if (node >= N) return;
    const float4* xw4 = (const float4*)xw;
    float di = dinv[node];
    float4 s = xw4[(size_t)node * G + q];
    float d2 = di * di;
    float4 a0 = {d2 * s.x, d2 * s.y, d2 * s.z, d2 * s.w};
    float4 a1 = {0.f, 0.f, 0.f, 0.f};
    float4 a2 = {0.f, 0.f, 0.f, 0.f};
    float4 a3 = {0.f, 0.f, 0.f, 0.f};
    int beg = row_ptr[node];
    int end = row_ptr[node + 1];
    int j = beg;
    for (; j + 3 < end; j += 4) {
        int2 p0 = perm[j];
        int2 p1 = perm[j + 1];
        int2 p2 = perm[j + 2];
        int2 p3 = perm[j + 3];
        float4 v0 = xw4[(size_t)p0.x * G + q];
        float4 v1 = xw4[(size_t)p1.x * G + q];
        float4 v2 = xw4[(size_t)p2.x * G + q];
        float4 v3 = xw4[(size_t)p3.x * G + q];
        float n0 = __int_as_float(p0.y);
        float n1 = __int_as_float(p1.y);
        float n2 = __int_as_float(p2.y);
        float n3 = __int_as_float(p3.y);
        a0.x += n0 * v0.x; a0.y += n0 * v0.y; a0.z += n0 * v0.z; a0.w += n0 * v0.w;
        a1.x += n1 * v1.x; a1.y += n1 * v1.y; a1.z += n1 * v1.z; a1.w += n1 * v1.w;
        a2.x += n2 * v2.x; a2.y += n2 * v2.y; a2.z += n2 * v2.z; a2.w += n2 * v2.w;
        a3.x += n3 * v3.x; a3.y += n3 * v3.y; a3.z += n3 * v3.z; a3.w += n3 * v3.w;
    }
    for (; j < end; ++j) {
        int2 p0 = perm[j];
        float4 v0 = xw4[(size_t)p0.x * G + q];
        float n0 = __int_as_float(p0.y);
        a0.x += n0 * v0.x; a0.y += n0 * v0.y; a0.z += n0 * v0.z; a0.w += n0 * v0.w;
    }
    float4 r;
    r.x = (a0.x + a1.x) + (a2.x + a3.x);
    r.y = (a0.y + a1.y) + (a2.y + a3.y);
    r.z = (a0.z + a1.z) + (a2.z + a3.z);
    r.w = (a0.w + a1.w) + (a2.w + a3.w);
    if (BIAS_ELU) {
        float4 b4 = ((const float4*)bias)[q];
        r.x += b4.x; r.y += b4.y; r.z += b4.z; r.w += b4.w;
        r.x = r.x > 0.f ? r.x : expm1f(r.x);
        r.y = r.y > 0.f ? r.y : expm1f(r.y);
        r.z = r.z > 0.f ? r.z : expm1f(r.z);
        r.w = r.w > 0.f ? r.w : expm1f(r.w);
    }
    ((float4*)out)[(size_t)node * G + q] = r;
}

extern "C" void kernel_launch(void* const* d_in, const int* in_sizes, int n_in,
                              void* d_out, int out_size, void* d_ws, size_t ws_size,
                              hipStream_t stream) {
    const float* x  = (const float*)d_in[0];
    const int*   ei = (const int*)d_in[1];
    const float* w  = (const float*)d_in[2];
    const float* W0 = (const float*)d_in[3];
    const float* b0 = (const float*)d_in[4];
    const float* W1 = (const float*)d_in[5];
    const float* b1 = (const float*)d_in[6];
    const float* W2 = (const float*)d_in[7];
    const float* b2 = (const float*)d_in[8];
    const float* Wm = (const float*)d_in[9];
    const float* bm = (const float*)d_in[10];
    float* out = (float*)d_out;

    const int N = in_sizes[0] / 256;
    const int E = in_sizes[2];
    const int* src = ei;
    const int* dst = ei + E;
    const int nbuck = (N + 255) >> 8;  // 256 nodes per bucket; requires N <= 131072

    char* ws = (char*)d_ws;
    size_t off = 0;
    auto alloc = [&](size_t bytes) {
        void* p = ws + off;
        off = (off + bytes + 255) & ~(size_t)255;
        return p;
    };
    float* dinv    = (float*)alloc((size_t)N * 4);
    int*   row_ptr = (int*)alloc(((size_t)N + 1) * 4);
    int*   bcnt    = (int*)alloc(520 * 4);
    int*   boff    = (int*)alloc(520 * 4);
    int*   gcur    = (int*)alloc(520 * 4);
    int2*  bedge   = (int2*)alloc((size_t)E * 8);
    int2*  perm    = (int2*)alloc((size_t)E * 8);
    float* BUF_A   = (float*)alloc((size_t)N * 32 * 4);
    float* BUF_B   = (float*)alloc((size_t)N * 32 * 4);

    hipMemsetAsync(bcnt, 0, 520 * 4, stream);

    const int CH = 8192;
    const int sblk = (E + CH - 1) / CH;

    // ---- build CSR (layer-invariant)
    bucket_hist<<<sblk, 256, 0, stream>>>(dst, bcnt, E, nbuck, CH);
    bucket_scan<<<1, 512, 0, stream>>>(bcnt, boff, gcur, nbuck);
    bucket_scatter<<<(E + 4095) / 4096, 256, 0, stream>>>(src, dst, w, gcur, bedge, E);
    sort_deg<<<nbuck, 256, 0, stream>>>(boff, bedge, row_ptr, dinv, N, E);
    sort_scatter<<<nbuck, 256, 0, stream>>>(boff, bedge, row_ptr, dinv, perm, N);

    // ---- layer 0: XW = x@W0 ; h1 = elu(A.XW + b0)
    gemm_x16<<<(N + 15) / 16, 256, 0, stream>>>(x, W0, BUF_A, N);
    agg4<16, true><<<(N + 63) / 64, 256, 0, stream>>>(row_ptr, perm, BUF_A, dinv, b0, BUF_B, N);

    // ---- layer 1: AG1 = A.h1 ; h2 = elu(AG1@W1 + b1)
    agg4<16, false><<<(N + 63) / 64, 256, 0, stream>>>(row_ptr, perm, BUF_B, dinv, nullptr, BUF_A, N);
    gemm_small<16, 32, true><<<(N + 7) / 8, 256, 0, stream>>>(BUF_A, W1, b1, BUF_B, N);

    // ---- layer 2: AG2 = A.h2 ; h3 = elu(AG2@W2 + b2)
    agg4<32, false><<<(N + 31) / 32, 256, 0, stream>>>(row_ptr, perm, BUF_B, dinv, nullptr, BUF_A, N);
    gemm_small<32, 32, true><<<(N + 7) / 8, 256, 0, stream>>>(BUF_A, W2, b2, BUF_B, N);

    // ---- head: out = h3@Wm + bm
    gemm_small<32, 16, false><<<(N + 15) / 16, 256, 0, stream>>>(BUF_B, Wm, bm, out, N);
}